// Round 2
// baseline (1339.917 us; speedup 1.0000x reference)
//
#include <hip/hip_runtime.h>

// BRITS-style recurrent imputation on MI355X.
// 8 batch-tiles(16 rows) x 32 H-chunks = 256 blocks; bt = blockIdx&7 so a
// tile's 32 blocks share one XCD under round-robin dispatch.
// R8: 3-tier validated transport. tier0 = nt loads (L1 no-allocate) straight
//     to VGPRs; tier1 = sc0 global_load_lds bounce; tier2 = agent-UC.
//     Double-sentinel validates each tier per tile at runtime.
// R9: parallel 4-wave LSTM epilogue; c-state in VGPR; gamma_h precomputed.
// R10: publish/detect chain de-hopped. (1) per-wave SUB-TAGS (4 dwords in
//      the chunk's 64B tag line), stored right after each wave's own h-ack:
//      b4 barrier + tid0 tag store deleted from the loop. (2) single-poller:
//      wave3 busy-polls all 128 sub-tags (dwordx4, no s_sleep), relays via
//      LDS flag; waves0-2 spin on LDS (no L2 traffic, no sleep quantization).
//      (3) ghL parity-double-buffered (b4 removal). (4) m-part gate MFMAs
//      under the h nt-load shadow. (5) k_prep: zero+msum blocks replaced by
//      hipMemsetAsync + msum fused into delta waves (exact int-float
//      atomicAdd); grid 7432->6856.

#define B_ 128
#define T_ 256
#define D_ 128
#define H_ 512

typedef _Float16 f16x8 __attribute__((ext_vector_type(8)));
typedef float    f32x4 __attribute__((ext_vector_type(4)));
typedef unsigned int u32x4 __attribute__((ext_vector_type(4)));

#define AS1 __attribute__((address_space(1)))
#define AS3 __attribute__((address_space(3)))

// ---- workspace layout (bytes), total 12,166,144 (< R1-proven 20,497,408) ----
#define OFF_HBUF   0u          // f16 [2][8 tiles][16KB frag-order]  262144
#define OFF_TAG    262144u     // uint [8][32][16] @64B/chunk, dwords0-3=wave subtags
#define OFF_DFLG   278528u     // uint [8][32] @64B        16384 (UC handshake flags)
#define OFF_DSNT   294912u     // uint [8][32] @64B        16384 (bounce-test sentinels)
#define OFF_DSN2   311296u     // uint [8][32] @64B        16384 (nt-test sentinels)
#define OFF_MSUM   327680u     // float [256]              1024
#define OFF_BG     328704u     // float [2048]             8192
#define OFF_WH     336896u     // f16 [8][16][64][8]       131072
#define OFF_WF     467968u     // f16 [8][4][64][8]        32768
#define OFF_WD     500736u     // f16 [32][4][64][8]       131072
#define OFF_GB     631808u     // f16 [32][4][24][64][8]   3145728
#define OFF_DBF    3777536u    // f16 [128][256][128]      8388608

__device__ __forceinline__ float sigm(float x)  { return __fdividef(1.0f, 1.0f + __expf(-x)); }
__device__ __forceinline__ float tanh_(float x) { return 1.0f - __fdividef(2.0f, __expf(2.0f*x) + 1.0f); }

// ---------------- fused pre-kernel ----------------
// (zeroing + out[0] + msum now handled by hipMemsetAsync / delta fusion)
// blk (rebased +576):
//        [576,704) delta (4 wave-units per block) + msum atomicAdd
//        [704,960) pack Wh | [960,1024) pack Wf | [1024,1280) pack Wdh
//        [1280,7424) pack gates | [7424,7432) pack bias
__global__ void k_prep(const float* __restrict__ data,
                       const float* __restrict__ W_ih, const float* __restrict__ W_hh,
                       const float* __restrict__ Wdh,  const float* __restrict__ Wh,
                       const float* __restrict__ Wf,
                       const float* __restrict__ b_ih, const float* __restrict__ b_hh,
                       unsigned char* __restrict__ ws, float* __restrict__ out)
{
  const int blk = blockIdx.x + 576, tid = threadIdx.x;
  if (blk < 704) {                              // delta: one 64-lane wave per (b, t-quarter)
    _Float16* dbf = (_Float16*)(ws + OFF_DBF);
    float* msum = (float*)(ws + OFF_MSUM);
    int wv = tid >> 6, ln = tid & 63;
    int unit = (blk - 576)*4 + wv;              // 0..511
    int b  = unit >> 2;
    int t0 = (unit & 3) * 64;
    __shared__ unsigned long long rm[4][65][2];
    for (int r = 0; r < 65; ++r) {
      int t = t0 - 1 + r;
      unsigned long long m0 = 0, m1 = 0;
      if (t >= 0) {
        const float* row = data + ((size_t)b*256 + t)*128;
        float a = row[ln], c = row[64 + ln];
        m0 = __ballot(a == a);
        m1 = __ballot(c == c);
      }
      // msum fusion: counts are integers -> float add is exact, order-free
      if (r > 0 && ln == 0)
        atomicAdd(msum + t, (float)(__popcll(m0) + __popcll(m1)));
      if (ln == 0) { rm[wv][r][0] = m0; rm[wv][r][1] = m1; }
    }
    // intra-wave LDS RAW is ordered (compiler lgkmcnt); no cross-wave sharing
    int t = t0 + ln;
    _Float16* orow = dbf + ((size_t)b*256 + t)*128;
    if (t == 0) {
      f16x8 z;
      #pragma unroll
      for (int i=0;i<8;i++) z[i] = (_Float16)0.0f;
      #pragma unroll
      for (int k=0;k<16;k++) ((f16x8*)orow)[k] = z;
      return;
    }
    unsigned long long mp0 = rm[wv][ln][0],   mp1 = rm[wv][ln][1];
    unsigned long long mt0 = rm[wv][ln+1][0], mt1 = rm[wv][ln+1][1];
    float carry = 0.0f;
    for (int g = 0; g < 16; ++g) {
      f16x8 v;
      #pragma unroll
      for (int j = 0; j < 8; ++j) {
        int d = g*8 + j;
        bool prevm = (d < 64)   ? ((mp0 >> d) & 1ull)   : ((mp1 >> (d-64)) & 1ull);
        int dm1 = (d - 1) & 127;
        bool leftm = (dm1 < 64) ? ((mt0 >> dm1) & 1ull) : ((mt1 >> (dm1-64)) & 1ull);
        float val = (!prevm) ? (carry + 1.0f) : (leftm ? 1.0f : 0.0f);
        carry = val;
        v[j] = (_Float16)val;
      }
      ((f16x8*)orow)[g] = v;
    }
    return;
  }
  if (blk < 960) {                              // pack Wh -> B-frag
    int id = (blk - 704)*256 + tid;             // [8][16][64][8]
    int j = id & 7, l = (id>>3)&63, ks = (id>>9)&15, nt = id>>13;
    int row = nt*16 + (l&15);
    int k   = ks*32 + ((l>>4)&3)*8 + j;
    ((_Float16*)(ws + OFF_WH))[id] = (_Float16)Wh[row*512 + k];
    return;
  }
  if (blk < 1024) {                             // pack Wf (off-diag masked)
    int id = (blk - 960)*256 + tid;             // [8][4][64][8]
    int j = id & 7, l = (id>>3)&63, ks = (id>>9)&3, nt = id>>11;
    int row = nt*16 + (l&15);
    int k   = ks*32 + ((l>>4)&3)*8 + j;
    float v = (row == k) ? 0.0f : Wf[row*128 + k];
    ((_Float16*)(ws + OFF_WF))[id] = (_Float16)v;
    return;
  }
  if (blk < 1280) {                             // pack Wdh
    int id = (blk - 1024)*256 + tid;            // [32][4][64][8]
    int j = id & 7, l = (id>>3)&63, ks = (id>>9)&3, c = id>>11;
    int row = c*16 + (l&15);
    int k   = ks*32 + ((l>>4)&3)*8 + j;
    ((_Float16*)(ws + OFF_WD))[id] = (_Float16)Wdh[row*128 + k];
    return;
  }
  if (blk < 7424) {                             // pack gates [32][4][24][64][8]
    int id = (blk - 1280)*256 + tid;
    int j = id & 7, l = (id>>3)&63;
    int f = id>>9;
    int ks = f % 24; f /= 24;
    int g = f & 3, c = f >> 2;
    int rn = g*512 + c*16 + (l&15);
    int k  = ks*32 + ((l>>4)&3)*8 + j;
    float v = (k < 256) ? W_ih[rn*256 + k] : W_hh[rn*512 + (k-256)];
    ((_Float16*)(ws + OFF_GB))[id] = (_Float16)v;
    return;
  }
  {                                             // bias
    int id = (blk - 7424)*256 + tid;            // 2048
    ((float*)(ws + OFF_BG))[id] = b_ih[id] + b_hh[id];
  }
}

// ---------------- main persistent kernel ----------------

__global__ __launch_bounds__(256, 1) void brits_main(
    const float* __restrict__ data,
    const float* __restrict__ bh,
    const float* __restrict__ bfv,
    const float* __restrict__ bdh,
    unsigned char* __restrict__ ws,
    float* __restrict__ out)
{
  const int bt  = blockIdx.x & 7;     // batch tile (== XCD under round-robin)
  const int ch  = blockIdx.x >> 3;    // H chunk 0..31
  const int tid = threadIdx.x;
  const int wv  = tid >> 6;           // wave 0..3
  const int ln  = tid & 63;
  const int l15 = ln & 15;
  const int lq  = ln >> 4;

  _Float16*       hbuf = (_Float16*)(ws + OFF_HBUF);
  unsigned int*   tag  = (unsigned int*)(ws + OFF_TAG);
  unsigned int*   dflg = (unsigned int*)(ws + OFF_DFLG);
  unsigned int*   dsnt = (unsigned int*)(ws + OFF_DSNT);
  unsigned int*   dsn2 = (unsigned int*)(ws + OFF_DSN2);
  const float*    msum = (const float*)(ws + OFF_MSUM);
  const float*    bgq  = (const float*)(ws + OFF_BG);
  const f16x8*    WhP  = (const f16x8*)(ws + OFF_WH);
  const f16x8*    WfP  = (const f16x8*)(ws + OFF_WF);
  const f16x8*    WdP  = (const f16x8*)(ws + OFF_WD);
  const f16x8*    GBP  = (const f16x8*)(ws + OFF_GB);
  const _Float16* dbf  = (const _Float16*)(ws + OFF_DBF);

  __shared__ __align__(16) _Float16 xcT[16][136];
  __shared__ __align__(16) _Float16 ccT[16][136];
  __shared__ __align__(16) _Float16 hstage[8192];    // tier-1 staging (16KB)
  __shared__ unsigned int sbounce[4][128];
  __shared__ float ccF[16][132];                     // fp32 c_c for out-stores
  __shared__ float gbuf[4][16][17];                  // +1 pad: kill 4-way conflicts
  __shared__ float ghL[2][16][17];                   // gamma_h(t+1), parity dbuf
  __shared__ float invms[256];
  __shared__ float bh_s[128], bf_s[128], bdh_s[16], bg_s[4][16];
  __shared__ float red[256];
  __shared__ int sNT[4], sB[4];
  __shared__ unsigned int hrdy;                      // LDS relay flag (mode 0)

  unsigned int* myflg  = dflg + ((bt<<5) + ch)*16;
  unsigned int* mysnt  = dsnt + ((bt<<5) + ch)*16;
  unsigned int* mysnt2 = dsn2 + ((bt<<5) + ch)*16;
  const unsigned int* pollflg  = dflg + ((bt<<5) + (ln & 31))*16;
  const unsigned int* sntslot  = dsnt + ((bt<<5) + (ln & 31))*16;
  const unsigned int* snt2slot = dsn2 + ((bt<<5) + (ln & 31))*16;

  auto gate = [&](unsigned thr){
    for (;;) {
      bool ok = true;
      if (ln < 32)
        ok = (__hip_atomic_load(pollflg, __ATOMIC_RELAXED,
                                __HIP_MEMORY_SCOPE_AGENT) & 15u) >= thr;
      if (__ballot(ok) == ~0ull) break;
      __builtin_amdgcn_s_sleep(8);
    }
  };
  auto setf = [&](unsigned v){
    if (tid == 0)
      __hip_atomic_store(myflg, v, __ATOMIC_RELAXED, __HIP_MEMORY_SCOPE_AGENT);
  };
  auto sentinel_write = [&](unsigned int* p, unsigned v, unsigned flagv){
    if (tid == 0) {
      *p = v;                                        // plain store -> own-XCD L2
      __asm__ __volatile__("" ::: "memory");
      __builtin_amdgcn_s_waitcnt(0);
      __hip_atomic_store(myflg, flagv, __ATOMIC_RELAXED, __HIP_MEMORY_SCOPE_AGENT);
    }
  };

  // ---------- tier-0 (nt) double-sentinel ----------
  sentinel_write(mysnt2, 0xC3000000u | (unsigned)(bt<<8) | (unsigned)ch, 1u);
  gate(1);
  bool nt1;
  { unsigned v = 0;
    if (ln < 32) v = __builtin_nontemporal_load(snt2slot);
    __asm__ __volatile__("" ::: "memory");
    nt1 = (__ballot(ln >= 32 ||
                    v == (0xC3000000u | (unsigned)(bt<<8) | (unsigned)(ln & 31))) == ~0ull); }
  __syncthreads();
  setf(2); gate(2);                                  // all blocks done phase-1 reads
  sentinel_write(mysnt2, 0x3C000000u | (unsigned)(bt<<8) | (unsigned)ch, 3u);
  gate(3);
  bool nt2;
  { unsigned v = 0;
    if (ln < 32) v = __builtin_nontemporal_load(snt2slot);
    __asm__ __volatile__("" ::: "memory");
    nt2 = (__ballot(ln >= 32 ||
                    v == (0x3C000000u | (unsigned)(bt<<8) | (unsigned)(ln & 31))) == ~0ull); }
  __syncthreads();
  setf(4); gate(4);
  // ---------- tier-1 (sc0 bounce) double-sentinel ----------
  sentinel_write(mysnt, 0xA5000000u | (unsigned)(bt<<8) | (unsigned)ch, 5u);
  gate(5);
  bool b1;
  { if (ln < 32)
      __builtin_amdgcn_global_load_lds((const AS1 void*)sntslot,
          (AS3 void*)&sbounce[wv][0], 4, 0, 1 /*sc0*/);
    __asm__ __volatile__("" ::: "memory");
    __builtin_amdgcn_s_waitcnt(0);
    __asm__ __volatile__("" ::: "memory");
    b1 = (__ballot(ln >= 32 ||
                   sbounce[wv][ln] == (0xA5000000u | (unsigned)(bt<<8) | (unsigned)(ln & 31))) == ~0ull); }
  __syncthreads();
  setf(6); gate(6);
  sentinel_write(mysnt, 0x5A000000u | (unsigned)(bt<<8) | (unsigned)ch, 7u);
  gate(7);
  bool b2;
  { if (ln < 32)
      __builtin_amdgcn_global_load_lds((const AS1 void*)sntslot,
          (AS3 void*)&sbounce[wv][0], 4, 0, 1 /*sc0*/);
    __asm__ __volatile__("" ::: "memory");
    __builtin_amdgcn_s_waitcnt(0);
    __asm__ __volatile__("" ::: "memory");
    b2 = (__ballot(ln >= 32 ||
                   sbounce[wv][ln] == (0x5A000000u | (unsigned)(bt<<8) | (unsigned)(ln & 31))) == ~0ull); }
  __syncthreads();
  if (ln == 0) { sNT[wv] = (nt1 && nt2) ? 1 : 0; sB[wv] = (b1 && b2) ? 1 : 0; }
  __syncthreads();
  if (tid == 0) {
    unsigned f = 8u;
    if (sNT[0] && sNT[1] && sNT[2] && sNT[3]) f |= 16u;
    if (sB[0]  && sB[1]  && sB[2]  && sB[3])  f |= 32u;
    __hip_atomic_store(myflg, f, __ATOMIC_RELAXED, __HIP_MEMORY_SCOPE_AGENT);
  }
  int mode;                                          // 0=nt, 1=bounce, 2=UC (tile-uniform)
  { unsigned v = 0;
    for (;;) {
      bool ok = true;
      if (ln < 32) {
        v = __hip_atomic_load(pollflg, __ATOMIC_RELAXED, __HIP_MEMORY_SCOPE_AGENT);
        ok = (v & 15u) >= 8u;
      }
      if (__ballot(ok) == ~0ull) break;
      __builtin_amdgcn_s_sleep(8);
    }
    bool allnt = (__ballot(ln >= 32 || (v & 16u)) == ~0ull);
    bool allb  = (__ballot(ln >= 32 || (v & 32u)) == ~0ull);
    mode = allnt ? 0 : (allb ? 1 : 2);
  }

  invms[tid] = 1.0f / (msum[tid] + 1e-5f);
  if (tid < 128) { bh_s[tid] = bh[tid]; bf_s[tid] = bfv[tid]; }
  if (tid < 16)  bdh_s[tid] = bdh[ch*16 + tid];
  if (tid < 64)  bg_s[tid>>4][tid&15] = bgq[(tid>>4)*512 + ch*16 + (tid&15)];
  if (tid == 0)  hrdy = 0u;
  __syncthreads();

  // ---- persistent weight fragments in VGPRs ----
  f16x8 WhB[2][16], WfB[2][4], GB[24], WdB[4];
  #pragma unroll
  for (int i=0;i<2;i++)
    #pragma unroll
    for (int ks=0;ks<16;ks++)
      WhB[i][ks] = WhP[((2*wv+i)*16 + ks)*64 + ln];
  #pragma unroll
  for (int i=0;i<2;i++)
    #pragma unroll
    for (int ks=0;ks<4;ks++)
      WfB[i][ks] = WfP[((2*wv+i)*4 + ks)*64 + ln];
  #pragma unroll
  for (int ks=0;ks<24;ks++)
    GB[ks] = GBP[((ch*4 + wv)*24 + ks)*64 + ln];
  #pragma unroll
  for (int ks=0;ks<4;ks++)
    WdB[ks] = WdP[(ch*4 + ks)*64 + ln];

  float loss_acc = 0.0f;
  const int rowg = bt*16;

  // parallel-epilogue lane ownership: one (row,col) of the 16x16 chunk tile
  const int erow = wv*4 + (ln >> 4);
  const int ecol = l15;
  const int gcol = ch*16 + ecol;                     // global h column
  const size_t e2 = ((size_t)((gcol >> 5)*64 + ((gcol >> 3) & 3)*16 + erow))*8 + (gcol & 7);
  float c_reg = 0.0f;                                // LSTM cell state, in-register

  unsigned int* tagw = tag + ((bt<<5) + ch)*16;      // this chunk's tag line (4 subtags)

  #pragma unroll 1
  for (int t = 0; t < 256; ++t) {
    // ---- prefetch everything that doesn't depend on h(t) ----
    float xnv[2][4], mmv[2][4];
    #pragma unroll
    for (int i=0;i<2;i++){
      int col = (2*wv+i)*16 + l15;
      #pragma unroll
      for (int r=0;r<4;r++){
        float dv = data[((rowg + lq*4 + r)*256 + t)*128 + col];
        bool ok = (dv == dv);
        xnv[i][r] = ok ? dv : 0.0f;
        mmv[i][r] = ok ? 1.0f : 0.0f;
      }
    }
    f16x8 mA[4];
    {
      const float* mrow = data + ((size_t)(rowg + l15)*256 + t)*128 + lq*8;
      #pragma unroll
      for (int k=0;k<4;k++){
        float4 a0 = *(const float4*)(mrow + k*32);
        float4 a1 = *(const float4*)(mrow + k*32 + 4);
        f16x8 mv;
        mv[0] = (a0.x==a0.x)?(_Float16)1.0f:(_Float16)0.0f;
        mv[1] = (a0.y==a0.y)?(_Float16)1.0f:(_Float16)0.0f;
        mv[2] = (a0.z==a0.z)?(_Float16)1.0f:(_Float16)0.0f;
        mv[3] = (a0.w==a0.w)?(_Float16)1.0f:(_Float16)0.0f;
        mv[4] = (a1.x==a1.x)?(_Float16)1.0f:(_Float16)0.0f;
        mv[5] = (a1.y==a1.y)?(_Float16)1.0f:(_Float16)0.0f;
        mv[6] = (a1.z==a1.z)?(_Float16)1.0f:(_Float16)0.0f;
        mv[7] = (a1.w==a1.w)?(_Float16)1.0f:(_Float16)0.0f;
        mA[k] = mv;
      }
    }
    // gamma_h(t+1): fully h-independent, hoisted into the wait window.
    // Parity-double-buffered (no b4): write slot (t+1)&1, read same slot in
    // THIS iteration's epilogue; b1..b3 separate write from read.
    if (wv == 0 && t < 255) {
      f16x8 dA[4];
      #pragma unroll
      for (int k=0;k<4;k++)
        dA[k] = *(const f16x8*)(dbf + ((size_t)(rowg+l15)*256 + (t+1))*128 + k*32 + lq*8);
      f32x4 ga = {0.f,0.f,0.f,0.f};
      #pragma unroll
      for (int k=0;k<4;k++)
        ga = __builtin_amdgcn_mfma_f32_16x16x32_f16(dA[k], WdB[k], ga, 0,0,0);
      #pragma unroll
      for (int r=0;r<4;r++)
        ghL[(t+1)&1][lq*4 + r][l15] = __expf(-fmaxf(ga[r] + bdh_s[l15], 0.0f));
    }

    // ---- wait for h(t): all 128 subtags >= t ----
    if (t > 0) {
      if (mode == 0) {
        if (wv == 3) {
          // single poller: 32 lanes x dwordx4 covers all 128 subtags, busy-spin
          for (;;) {
            bool ok = true;
            if (ln < 32) {
              u32x4 tv = __builtin_nontemporal_load((const u32x4*)(tag + ((bt<<5) + ln)*16));
              ok = tv[0] >= (unsigned)t && tv[1] >= (unsigned)t &&
                   tv[2] >= (unsigned)t && tv[3] >= (unsigned)t;
            }
            __asm__ __volatile__("" ::: "memory");
            if (__ballot(ok) == ~0ull) break;
          }
          if (ln == 0)
            __hip_atomic_store(&hrdy, (unsigned)t, __ATOMIC_RELAXED,
                               __HIP_MEMORY_SCOPE_WORKGROUP);
        } else {
          // LDS relay spin: no L2 traffic, fast wake
          while (__hip_atomic_load(&hrdy, __ATOMIC_RELAXED,
                                   __HIP_MEMORY_SCOPE_WORKGROUP) < (unsigned)t) {}
        }
      } else if (mode == 1) {
        for (;;) {
          if (ln < 32)
            __builtin_amdgcn_global_load_lds((const AS1 void*)(tag + ((bt<<5) + ln)*16),
                (AS3 void*)&sbounce[wv][0], 16, 0, 1 /*sc0*/);
          __asm__ __volatile__("" ::: "memory");
          __builtin_amdgcn_s_waitcnt(0);
          __asm__ __volatile__("" ::: "memory");
          bool ok = true;
          if (ln < 32)
            ok = sbounce[wv][ln*4+0] >= (unsigned)t && sbounce[wv][ln*4+1] >= (unsigned)t &&
                 sbounce[wv][ln*4+2] >= (unsigned)t && sbounce[wv][ln*4+3] >= (unsigned)t;
          if (__ballot(ok) == ~0ull) break;
          __builtin_amdgcn_s_sleep(1);
        }
      } else {
        for (;;) {
          // each lane checks 2 of the 128 subtags
          const unsigned int* p = tag + ((bt<<5) + (ln>>1))*16 + (ln&1)*2;
          unsigned v0 = __hip_atomic_load(p,     __ATOMIC_RELAXED, __HIP_MEMORY_SCOPE_AGENT);
          unsigned v1 = __hip_atomic_load(p + 1, __ATOMIC_RELAXED, __HIP_MEMORY_SCOPE_AGENT);
          bool ok = v0 >= (unsigned)t && v1 >= (unsigned)t;
          if (__ballot(ok) == ~0ull) break;
          __builtin_amdgcn_s_sleep(1);
        }
      }
    }

    // ---- h A-fragments ----
    f16x8 hA[16];
    const char* hbB = (const char*)hbuf + (size_t)(((t&1)*8 + bt))*16384;
    if (mode == 0) {
      // direct nt loads: fragment-order layout is lane-linear (ln*16 per ks)
      #pragma unroll
      for (int ks=0;ks<16;ks++) {
        u32x4 hv = __builtin_nontemporal_load((const u32x4*)(hbB + ks*1024 + ln*16));
        hA[ks] = __builtin_bit_cast(f16x8, hv);
      }
    } else if (mode == 1) {
      #pragma unroll
      for (int s=0;s<4;s++){
        int off = s*4096 + wv*1024;
        __builtin_amdgcn_global_load_lds((const AS1 void*)(hbB + off + ln*16),
            (AS3 void*)((char*)hstage + off), 16, 0, 1 /*sc0*/);
      }
      __asm__ __volatile__("" ::: "memory");
      __builtin_amdgcn_s_waitcnt(0);
      __syncthreads();
      #pragma unroll
      for (int ks=0;ks<16;ks++)
        hA[ks] = *(const f16x8*)((const char*)hstage + ks*1024 + ln*16);
    } else {
      #pragma unroll
      for (int ks=0;ks<16;ks++) {
        const char* p = hbB + (size_t)(ks*64 + ln)*16;
        union { unsigned long long u[2]; f16x8 v; } cv;
        cv.u[0] = __hip_atomic_load((const unsigned long long*)p,
                                    __ATOMIC_RELAXED, __HIP_MEMORY_SCOPE_AGENT);
        cv.u[1] = __hip_atomic_load((const unsigned long long*)(p + 8),
                                    __ATOMIC_RELAXED, __HIP_MEMORY_SCOPE_AGENT);
        hA[ks] = cv.v;
      }
    }

    // ---- MFMAs: m-part first (executes under h nt-load shadow), then
    //      x_h chains + gate h-parts (6 concurrent accums) ----
    f32x4 g0 = {0.f,0.f,0.f,0.f}, g1 = {0.f,0.f,0.f,0.f};
    #pragma unroll
    for (int k=0;k<4;k++)
      g0 = __builtin_amdgcn_mfma_f32_16x16x32_f16(mA[k], GB[4+k], g0, 0,0,0);
    f32x4 xA0[2], xA1[2];
    #pragma unroll
    for (int i=0;i<2;i++){
      f32x4 a0 = {0.f,0.f,0.f,0.f}, a1 = {0.f,0.f,0.f,0.f};
      #pragma unroll
      for (int ks=0;ks<8;ks++){
        a0 = __builtin_amdgcn_mfma_f32_16x16x32_f16(hA[ks],   WhB[i][ks],   a0, 0,0,0);
        a1 = __builtin_amdgcn_mfma_f32_16x16x32_f16(hA[ks+8], WhB[i][ks+8], a1, 0,0,0);
      }
      xA0[i] = a0; xA1[i] = a1;
    }
    #pragma unroll
    for (int ks=0;ks<8;ks++)
      g0 = __builtin_amdgcn_mfma_f32_16x16x32_f16(hA[ks], GB[8+ks], g0, 0,0,0);
    #pragma unroll
    for (int ks=0;ks<8;ks++)
      g1 = __builtin_amdgcn_mfma_f32_16x16x32_f16(hA[8+ks], GB[16+ks], g1, 0,0,0);

    // ---- x_h epilogue: sigmoid, loss1, x_c -> xcT ----
    float xhv[2][4];
    float numer = 0.0f;
    #pragma unroll
    for (int i=0;i<2;i++){
      int col = (2*wv+i)*16 + l15;
      float bhc = bh_s[col];
      #pragma unroll
      for (int r=0;r<4;r++){
        float s = sigm(xA0[i][r] + xA1[i][r] + bhc);
        xhv[i][r] = s;
        numer += fabsf(xnv[i][r] - s) * mmv[i][r];
        float xc = (mmv[i][r] > 0.f) ? xnv[i][r] : s;
        xcT[lq*4 + r][col] = (_Float16)xc;
      }
    }
    __syncthreads();                               // b1

    // ---- z_h MFMAs ----
    f16x8 xcA[4];
    #pragma unroll
    for (int k=0;k<4;k++)
      xcA[k] = *(const f16x8*)(&xcT[l15][k*32 + lq*8]);
    f32x4 z0 = {0.f,0.f,0.f,0.f}, z1 = {0.f,0.f,0.f,0.f};
    #pragma unroll
    for (int ks=0;ks<4;ks++){
      z0 = __builtin_amdgcn_mfma_f32_16x16x32_f16(xcA[ks], WfB[0][ks], z0, 0,0,0);
      z1 = __builtin_amdgcn_mfma_f32_16x16x32_f16(xcA[ks], WfB[1][ks], z1, 0,0,0);
    }

    // ---- z_h epilogue: loss2, c_c (fp32 to ccF, f16 to ccT) ----
    #pragma unroll
    for (int i=0;i<2;i++){
      f32x4 a = (i==0) ? z0 : z1;
      int col = (2*wv+i)*16 + l15;
      float bfc = bf_s[col];
      #pragma unroll
      for (int r=0;r<4;r++){
        float z = sigm(a[r] + bfc);
        numer += fabsf(xnv[i][r] - z) * mmv[i][r];
        float chv = fabsf(0.5f*z + 0.5f*xhv[i][r]);
        float cc  = (mmv[i][r] > 0.f) ? xnv[i][r] : chv;
        int row = lq*4 + r;
        ccT[row][col] = (_Float16)cc;
        ccF[row][col] = cc;
      }
    }
    if (ch == 0) loss_acc += numer * invms[t];
    __syncthreads();                               // b2

    // ---- gates: add c_c part, stash per-gate partials ----
    f16x8 ccA[4];
    #pragma unroll
    for (int k=0;k<4;k++)
      ccA[k] = *(const f16x8*)(&ccT[l15][k*32 + lq*8]);
    #pragma unroll
    for (int k=0;k<4;k++)
      g0 = __builtin_amdgcn_mfma_f32_16x16x32_f16(ccA[k], GB[k], g0, 0,0,0);
    #pragma unroll
    for (int r=0;r<4;r++) gbuf[wv][lq*4 + r][l15] = g0[r] + g1[r];
    __syncthreads();                               // b3

    // ---- parallel epilogue: per-wave h publish + per-wave subtag; NO b4.
    //      Cross-iteration LDS hazards are covered by the b1/b2/b3 chain. ----
    {
      float ii = gbuf[0][erow][ecol] + bg_s[0][ecol];
      float ff = gbuf[1][erow][ecol] + bg_s[1][ecol];
      float gg = gbuf[2][erow][ecol] + bg_s[2][ecol];
      float oo = gbuf[3][erow][ecol] + bg_s[3][ecol];
      float cn = sigm(ff)*c_reg + sigm(ii)*tanh_(gg);
      c_reg = cn;
      if (t < 255) {
        float hn = sigm(oo)*tanh_(cn) * ghL[(t+1)&1][erow][ecol];
        _Float16 hf = (_Float16)hn;
        char* dp = (char*)hbuf + (size_t)((((t+1)&1)*8 + bt))*16384 + e2*2;
        unsigned tv = (unsigned)(t+1);
        if (mode < 2) {
          *(_Float16*)dp = hf;                     // coalesced 64B-line stores
          __asm__ __volatile__("" ::: "memory");
          __builtin_amdgcn_s_waitcnt(0);           // this wave's h in L2 ...
          __asm__ __volatile__("" ::: "memory");
          if (ln == 0) tagw[wv] = tv;              // ... before its subtag
          __asm__ __volatile__("" ::: "memory");
        } else {
          union { _Float16 f; unsigned short u; } cv2; cv2.f = hf;
          __hip_atomic_store((unsigned short*)dp, cv2.u,
                             __ATOMIC_RELAXED, __HIP_MEMORY_SCOPE_AGENT);
          __atomic_signal_fence(__ATOMIC_SEQ_CST);
          __builtin_amdgcn_s_waitcnt(0);
          __atomic_signal_fence(__ATOMIC_SEQ_CST);
          if (ln == 0)
            __hip_atomic_store(tagw + wv, tv,
                               __ATOMIC_RELAXED, __HIP_MEMORY_SCOPE_AGENT);
        }
      }
    }
    // out-stores issued AFTER the subtag store: fire-and-forget into the
    // next poll window
    if (wv == 1) {
      int row = ln >> 2, col = ch*4 + (ln & 3);
      out[1 + ((size_t)(rowg+row)*256 + t)*128 + col] = ccF[row][col];
    }
  }

  // ---- loss reduction (chunk-0 blocks only) ----
  if (ch == 0) {
    red[tid] = loss_acc;
    __syncthreads();
    if (tid == 0) {
      float s = 0.f;
      for (int i=0;i<256;i++) s += red[i];
      atomicAdd(out, 0.3f * s);
    }
  }
}

// ---------------- launch ----------------

extern "C" void kernel_launch(void* const* d_in, const int* in_sizes, int n_in,
                              void* d_out, int out_size, void* d_ws, size_t ws_size,
                              hipStream_t stream) {
  const float* data = (const float*)d_in[0];
  const float* W_ih = (const float*)d_in[1];
  const float* b_ih = (const float*)d_in[2];
  const float* W_hh = (const float*)d_in[3];
  const float* b_hh = (const float*)d_in[4];
  const float* Wdh  = (const float*)d_in[5];
  const float* bdh  = (const float*)d_in[6];
  // d_in[7] Wdx, d_in[8] bdx: dead code in reference forward
  const float* Wh   = (const float*)d_in[9];
  const float* bh   = (const float*)d_in[10];
  const float* Wf   = (const float*)d_in[11];
  const float* bf   = (const float*)d_in[12];
  // d_in[13] Wc, d_in[14] bc: dead code
  float* out = (float*)d_out;
  unsigned char* ws = (unsigned char*)d_ws;

  // zero hbuf+tag+dflg+dsnt+dsn2+msum (control regions) and out[0] each launch
  hipMemsetAsync(ws, 0, OFF_MSUM + 1024u, stream);
  hipMemsetAsync(out, 0, 4, stream);
  k_prep     <<<6856, 256, 0, stream>>>(data, W_ih, W_hh, Wdh, Wh, Wf,
                                        b_ih, b_hh, ws, out);
  brits_main <<<256,  256, 0, stream>>>(data, bh, bf, bdh, ws, out);
}

// Round 4
// 1265.531 us; speedup vs baseline: 1.0588x; 1.0588x over previous
//
#include <hip/hip_runtime.h>

// BRITS-style recurrent imputation on MI355X.
// 8 batch-tiles(16 rows) x 32 H-chunks = 256 blocks; bt = blockIdx&7 so a
// tile's 32 blocks share one XCD under round-robin dispatch.
// R8: 3-tier validated transport. tier0 = nt loads (L1 no-allocate) straight
//     to VGPRs; tier1 = sc0 global_load_lds bounce; tier2 = agent-UC.
//     Double-sentinel validates each tier per tile at runtime.
// R9: parallel 4-wave LSTM epilogue; c-state in VGPR; gamma_h precomputed.
// R10: per-wave SUB-TAGS stored right after each wave's own h-ack (b4 barrier
//      + tid0 tag store deleted); single-poller wave3 busy-polls all 128
//      sub-tags (dwordx4, no s_sleep) and relays via LDS flag; ghL parity
//      double-buffered; m-part gate MFMAs under the h nt-load shadow.
// R11: launch-side revert. R10's hipMemsetAsync + atomicAdd-msum fusion cost
//      ~97us of pre-main overhead (serialized memset dispatches + 32k atomics
//      on 256 addresses). Restore R9's k_prep (in-kernel zeroing + popcount
//      msum, grid 7432, no memsets); keep R10 brits_main verbatim.
// R12: resubmit of R11 verbatim — R3 bench was an infra failure (container
//      died twice), no measurement was taken.

#define B_ 128
#define T_ 256
#define D_ 128
#define H_ 512

typedef _Float16 f16x8 __attribute__((ext_vector_type(8)));
typedef float    f32x4 __attribute__((ext_vector_type(4)));
typedef unsigned int u32x4 __attribute__((ext_vector_type(4)));

#define AS1 __attribute__((address_space(1)))
#define AS3 __attribute__((address_space(3)))

// ---- workspace layout (bytes), total 12,166,144 (< R1-proven 20,497,408) ----
#define OFF_HBUF   0u          // f16 [2][8 tiles][16KB frag-order]  262144
#define OFF_TAG    262144u     // uint [8][32][16] @64B/chunk, dwords0-3=wave subtags
#define OFF_DFLG   278528u     // uint [8][32] @64B        16384 (UC handshake flags)
#define OFF_DSNT   294912u     // uint [8][32] @64B        16384 (bounce-test sentinels)
#define OFF_DSN2   311296u     // uint [8][32] @64B        16384 (nt-test sentinels)
#define OFF_MSUM   327680u     // float [256]              1024
#define OFF_BG     328704u     // float [2048]             8192
#define OFF_WH     336896u     // f16 [8][16][64][8]       131072
#define OFF_WF     467968u     // f16 [8][4][64][8]        32768
#define OFF_WD     500736u     // f16 [32][4][64][8]       131072
#define OFF_GB     631808u     // f16 [32][4][24][64][8]   3145728
#define OFF_DBF    3777536u    // f16 [128][256][128]      8388608

__device__ __forceinline__ float sigm(float x)  { return __fdividef(1.0f, 1.0f + __expf(-x)); }
__device__ __forceinline__ float tanh_(float x) { return 1.0f - __fdividef(2.0f, __expf(2.0f*x) + 1.0f); }

// ---------------- fused pre-kernel ----------------
// blocks [0,320) zero ws control regions + out[0]
//        [320,576) msum per t (popcount, no atomics)
//        [576,704) delta (4 wave-units per block)
//        [704,960) pack Wh | [960,1024) pack Wf | [1024,1280) pack Wdh
//        [1280,7424) pack gates | [7424,7432) pack bias
__global__ void k_prep(const float* __restrict__ data,
                       const float* __restrict__ W_ih, const float* __restrict__ W_hh,
                       const float* __restrict__ Wdh,  const float* __restrict__ Wh,
                       const float* __restrict__ Wf,
                       const float* __restrict__ b_ih, const float* __restrict__ b_hh,
                       unsigned char* __restrict__ ws, float* __restrict__ out)
{
  const int blk = blockIdx.x, tid = threadIdx.x;
  if (blk < 320) {
    ((unsigned int*)ws)[blk*256 + tid] = 0u;    // hbuf+tag+dflg+dsnt+dsn2 = 81920 words
    if (blk == 0 && tid == 0) out[0] = 0.0f;
    return;
  }
  if (blk < 576) {                              // msum[t]
    int t = blk - 320;
    int cnt = 0;
    for (int i = 0; i < 64; ++i) {
      int e = tid + 256*i;                      // 0..16383
      int b = e >> 7, d = e & 127;
      float v = data[((size_t)(b*256) + t)*128 + d];
      cnt += (v == v) ? 1 : 0;
    }
    __shared__ int ism[256];
    ism[tid] = cnt;
    __syncthreads();
    if (tid == 0) {
      int s = 0;
      for (int i = 0; i < 256; ++i) s += ism[i];
      ((float*)(ws + OFF_MSUM))[t] = (float)s;
    }
    return;
  }
  if (blk < 704) {                              // delta: one 64-lane wave per (b, t-quarter)
    _Float16* dbf = (_Float16*)(ws + OFF_DBF);
    int wv = tid >> 6, ln = tid & 63;
    int unit = (blk - 576)*4 + wv;              // 0..511
    int b  = unit >> 2;
    int t0 = (unit & 3) * 64;
    __shared__ unsigned long long rm[4][65][2];
    for (int r = 0; r < 65; ++r) {
      int t = t0 - 1 + r;
      unsigned long long m0 = 0, m1 = 0;
      if (t >= 0) {
        const float* row = data + ((size_t)b*256 + t)*128;
        float a = row[ln], c = row[64 + ln];
        m0 = __ballot(a == a);
        m1 = __ballot(c == c);
      }
      if (ln == 0) { rm[wv][r][0] = m0; rm[wv][r][1] = m1; }
    }
    // intra-wave LDS RAW is ordered (compiler lgkmcnt); no cross-wave sharing
    int t = t0 + ln;
    _Float16* orow = dbf + ((size_t)b*256 + t)*128;
    if (t == 0) {
      f16x8 z;
      #pragma unroll
      for (int i=0;i<8;i++) z[i] = (_Float16)0.0f;
      #pragma unroll
      for (int k=0;k<16;k++) ((f16x8*)orow)[k] = z;
      return;
    }
    unsigned long long mp0 = rm[wv][ln][0],   mp1 = rm[wv][ln][1];
    unsigned long long mt0 = rm[wv][ln+1][0], mt1 = rm[wv][ln+1][1];
    float carry = 0.0f;
    for (int g = 0; g < 16; ++g) {
      f16x8 v;
      #pragma unroll
      for (int j = 0; j < 8; ++j) {
        int d = g*8 + j;
        bool prevm = (d < 64)   ? ((mp0 >> d) & 1ull)   : ((mp1 >> (d-64)) & 1ull);
        int dm1 = (d - 1) & 127;
        bool leftm = (dm1 < 64) ? ((mt0 >> dm1) & 1ull) : ((mt1 >> (dm1-64)) & 1ull);
        float val = (!prevm) ? (carry + 1.0f) : (leftm ? 1.0f : 0.0f);
        carry = val;
        v[j] = (_Float16)val;
      }
      ((f16x8*)orow)[g] = v;
    }
    return;
  }
  if (blk < 960) {                              // pack Wh -> B-frag
    int id = (blk - 704)*256 + tid;             // [8][16][64][8]
    int j = id & 7, l = (id>>3)&63, ks = (id>>9)&15, nt = id>>13;
    int row = nt*16 + (l&15);
    int k   = ks*32 + ((l>>4)&3)*8 + j;
    ((_Float16*)(ws + OFF_WH))[id] = (_Float16)Wh[row*512 + k];
    return;
  }
  if (blk < 1024) {                             // pack Wf (off-diag masked)
    int id = (blk - 960)*256 + tid;             // [8][4][64][8]
    int j = id & 7, l = (id>>3)&63, ks = (id>>9)&3, nt = id>>11;
    int row = nt*16 + (l&15);
    int k   = ks*32 + ((l>>4)&3)*8 + j;
    float v = (row == k) ? 0.0f : Wf[row*128 + k];
    ((_Float16*)(ws + OFF_WF))[id] = (_Float16)v;
    return;
  }
  if (blk < 1280) {                             // pack Wdh
    int id = (blk - 1024)*256 + tid;            // [32][4][64][8]
    int j = id & 7, l = (id>>3)&63, ks = (id>>9)&3, c = id>>11;
    int row = c*16 + (l&15);
    int k   = ks*32 + ((l>>4)&3)*8 + j;
    ((_Float16*)(ws + OFF_WD))[id] = (_Float16)Wdh[row*128 + k];
    return;
  }
  if (blk < 7424) {                             // pack gates [32][4][24][64][8]
    int id = (blk - 1280)*256 + tid;
    int j = id & 7, l = (id>>3)&63;
    int f = id>>9;
    int ks = f % 24; f /= 24;
    int g = f & 3, c = f >> 2;
    int rn = g*512 + c*16 + (l&15);
    int k  = ks*32 + ((l>>4)&3)*8 + j;
    float v = (k < 256) ? W_ih[rn*256 + k] : W_hh[rn*512 + (k-256)];
    ((_Float16*)(ws + OFF_GB))[id] = (_Float16)v;
    return;
  }
  {                                             // bias
    int id = (blk - 7424)*256 + tid;            // 2048
    ((float*)(ws + OFF_BG))[id] = b_ih[id] + b_hh[id];
  }
}

// ---------------- main persistent kernel ----------------

__global__ __launch_bounds__(256, 1) void brits_main(
    const float* __restrict__ data,
    const float* __restrict__ bh,
    const float* __restrict__ bfv,
    const float* __restrict__ bdh,
    unsigned char* __restrict__ ws,
    float* __restrict__ out)
{
  const int bt  = blockIdx.x & 7;     // batch tile (== XCD under round-robin)
  const int ch  = blockIdx.x >> 3;    // H chunk 0..31
  const int tid = threadIdx.x;
  const int wv  = tid >> 6;           // wave 0..3
  const int ln  = tid & 63;
  const int l15 = ln & 15;
  const int lq  = ln >> 4;

  _Float16*       hbuf = (_Float16*)(ws + OFF_HBUF);
  unsigned int*   tag  = (unsigned int*)(ws + OFF_TAG);
  unsigned int*   dflg = (unsigned int*)(ws + OFF_DFLG);
  unsigned int*   dsnt = (unsigned int*)(ws + OFF_DSNT);
  unsigned int*   dsn2 = (unsigned int*)(ws + OFF_DSN2);
  const float*    msum = (const float*)(ws + OFF_MSUM);
  const float*    bgq  = (const float*)(ws + OFF_BG);
  const f16x8*    WhP  = (const f16x8*)(ws + OFF_WH);
  const f16x8*    WfP  = (const f16x8*)(ws + OFF_WF);
  const f16x8*    WdP  = (const f16x8*)(ws + OFF_WD);
  const f16x8*    GBP  = (const f16x8*)(ws + OFF_GB);
  const _Float16* dbf  = (const _Float16*)(ws + OFF_DBF);

  __shared__ __align__(16) _Float16 xcT[16][136];
  __shared__ __align__(16) _Float16 ccT[16][136];
  __shared__ __align__(16) _Float16 hstage[8192];    // tier-1 staging (16KB)
  __shared__ unsigned int sbounce[4][128];
  __shared__ float ccF[16][132];                     // fp32 c_c for out-stores
  __shared__ float gbuf[4][16][17];                  // +1 pad: kill 4-way conflicts
  __shared__ float ghL[2][16][17];                   // gamma_h(t+1), parity dbuf
  __shared__ float invms[256];
  __shared__ float bh_s[128], bf_s[128], bdh_s[16], bg_s[4][16];
  __shared__ float red[256];
  __shared__ int sNT[4], sB[4];
  __shared__ unsigned int hrdy;                      // LDS relay flag (mode 0)

  unsigned int* myflg  = dflg + ((bt<<5) + ch)*16;
  unsigned int* mysnt  = dsnt + ((bt<<5) + ch)*16;
  unsigned int* mysnt2 = dsn2 + ((bt<<5) + ch)*16;
  const unsigned int* pollflg  = dflg + ((bt<<5) + (ln & 31))*16;
  const unsigned int* sntslot  = dsnt + ((bt<<5) + (ln & 31))*16;
  const unsigned int* snt2slot = dsn2 + ((bt<<5) + (ln & 31))*16;

  auto gate = [&](unsigned thr){
    for (;;) {
      bool ok = true;
      if (ln < 32)
        ok = (__hip_atomic_load(pollflg, __ATOMIC_RELAXED,
                                __HIP_MEMORY_SCOPE_AGENT) & 15u) >= thr;
      if (__ballot(ok) == ~0ull) break;
      __builtin_amdgcn_s_sleep(8);
    }
  };
  auto setf = [&](unsigned v){
    if (tid == 0)
      __hip_atomic_store(myflg, v, __ATOMIC_RELAXED, __HIP_MEMORY_SCOPE_AGENT);
  };
  auto sentinel_write = [&](unsigned int* p, unsigned v, unsigned flagv){
    if (tid == 0) {
      *p = v;                                        // plain store -> own-XCD L2
      __asm__ __volatile__("" ::: "memory");
      __builtin_amdgcn_s_waitcnt(0);
      __hip_atomic_store(myflg, flagv, __ATOMIC_RELAXED, __HIP_MEMORY_SCOPE_AGENT);
    }
  };

  // ---------- tier-0 (nt) double-sentinel ----------
  sentinel_write(mysnt2, 0xC3000000u | (unsigned)(bt<<8) | (unsigned)ch, 1u);
  gate(1);
  bool nt1;
  { unsigned v = 0;
    if (ln < 32) v = __builtin_nontemporal_load(snt2slot);
    __asm__ __volatile__("" ::: "memory");
    nt1 = (__ballot(ln >= 32 ||
                    v == (0xC3000000u | (unsigned)(bt<<8) | (unsigned)(ln & 31))) == ~0ull); }
  __syncthreads();
  setf(2); gate(2);                                  // all blocks done phase-1 reads
  sentinel_write(mysnt2, 0x3C000000u | (unsigned)(bt<<8) | (unsigned)ch, 3u);
  gate(3);
  bool nt2;
  { unsigned v = 0;
    if (ln < 32) v = __builtin_nontemporal_load(snt2slot);
    __asm__ __volatile__("" ::: "memory");
    nt2 = (__ballot(ln >= 32 ||
                    v == (0x3C000000u | (unsigned)(bt<<8) | (unsigned)(ln & 31))) == ~0ull); }
  __syncthreads();
  setf(4); gate(4);
  // ---------- tier-1 (sc0 bounce) double-sentinel ----------
  sentinel_write(mysnt, 0xA5000000u | (unsigned)(bt<<8) | (unsigned)ch, 5u);
  gate(5);
  bool b1;
  { if (ln < 32)
      __builtin_amdgcn_global_load_lds((const AS1 void*)sntslot,
          (AS3 void*)&sbounce[wv][0], 4, 0, 1 /*sc0*/);
    __asm__ __volatile__("" ::: "memory");
    __builtin_amdgcn_s_waitcnt(0);
    __asm__ __volatile__("" ::: "memory");
    b1 = (__ballot(ln >= 32 ||
                   sbounce[wv][ln] == (0xA5000000u | (unsigned)(bt<<8) | (unsigned)(ln & 31))) == ~0ull); }
  __syncthreads();
  setf(6); gate(6);
  sentinel_write(mysnt, 0x5A000000u | (unsigned)(bt<<8) | (unsigned)ch, 7u);
  gate(7);
  bool b2;
  { if (ln < 32)
      __builtin_amdgcn_global_load_lds((const AS1 void*)sntslot,
          (AS3 void*)&sbounce[wv][0], 4, 0, 1 /*sc0*/);
    __asm__ __volatile__("" ::: "memory");
    __builtin_amdgcn_s_waitcnt(0);
    __asm__ __volatile__("" ::: "memory");
    b2 = (__ballot(ln >= 32 ||
                   sbounce[wv][ln] == (0x5A000000u | (unsigned)(bt<<8) | (unsigned)(ln & 31))) == ~0ull); }
  __syncthreads();
  if (ln == 0) { sNT[wv] = (nt1 && nt2) ? 1 : 0; sB[wv] = (b1 && b2) ? 1 : 0; }
  __syncthreads();
  if (tid == 0) {
    unsigned f = 8u;
    if (sNT[0] && sNT[1] && sNT[2] && sNT[3]) f |= 16u;
    if (sB[0]  && sB[1]  && sB[2]  && sB[3])  f |= 32u;
    __hip_atomic_store(myflg, f, __ATOMIC_RELAXED, __HIP_MEMORY_SCOPE_AGENT);
  }
  int mode;                                          // 0=nt, 1=bounce, 2=UC (tile-uniform)
  { unsigned v = 0;
    for (;;) {
      bool ok = true;
      if (ln < 32) {
        v = __hip_atomic_load(pollflg, __ATOMIC_RELAXED, __HIP_MEMORY_SCOPE_AGENT);
        ok = (v & 15u) >= 8u;
      }
      if (__ballot(ok) == ~0ull) break;
      __builtin_amdgcn_s_sleep(8);
    }
    bool allnt = (__ballot(ln >= 32 || (v & 16u)) == ~0ull);
    bool allb  = (__ballot(ln >= 32 || (v & 32u)) == ~0ull);
    mode = allnt ? 0 : (allb ? 1 : 2);
  }

  invms[tid] = 1.0f / (msum[tid] + 1e-5f);
  if (tid < 128) { bh_s[tid] = bh[tid]; bf_s[tid] = bfv[tid]; }
  if (tid < 16)  bdh_s[tid] = bdh[ch*16 + tid];
  if (tid < 64)  bg_s[tid>>4][tid&15] = bgq[(tid>>4)*512 + ch*16 + (tid&15)];
  if (tid == 0)  hrdy = 0u;
  __syncthreads();

  // ---- persistent weight fragments in VGPRs ----
  f16x8 WhB[2][16], WfB[2][4], GB[24], WdB[4];
  #pragma unroll
  for (int i=0;i<2;i++)
    #pragma unroll
    for (int ks=0;ks<16;ks++)
      WhB[i][ks] = WhP[((2*wv+i)*16 + ks)*64 + ln];
  #pragma unroll
  for (int i=0;i<2;i++)
    #pragma unroll
    for (int ks=0;ks<4;ks++)
      WfB[i][ks] = WfP[((2*wv+i)*4 + ks)*64 + ln];
  #pragma unroll
  for (int ks=0;ks<24;ks++)
    GB[ks] = GBP[((ch*4 + wv)*24 + ks)*64 + ln];
  #pragma unroll
  for (int ks=0;ks<4;ks++)
    WdB[ks] = WdP[(ch*4 + ks)*64 + ln];

  float loss_acc = 0.0f;
  const int rowg = bt*16;

  // parallel-epilogue lane ownership: one (row,col) of the 16x16 chunk tile
  const int erow = wv*4 + (ln >> 4);
  const int ecol = l15;
  const int gcol = ch*16 + ecol;                     // global h column
  const size_t e2 = ((size_t)((gcol >> 5)*64 + ((gcol >> 3) & 3)*16 + erow))*8 + (gcol & 7);
  float c_reg = 0.0f;                                // LSTM cell state, in-register

  unsigned int* tagw = tag + ((bt<<5) + ch)*16;      // this chunk's tag line (4 subtags)

  #pragma unroll 1
  for (int t = 0; t < 256; ++t) {
    // ---- prefetch everything that doesn't depend on h(t) ----
    float xnv[2][4], mmv[2][4];
    #pragma unroll
    for (int i=0;i<2;i++){
      int col = (2*wv+i)*16 + l15;
      #pragma unroll
      for (int r=0;r<4;r++){
        float dv = data[((rowg + lq*4 + r)*256 + t)*128 + col];
        bool ok = (dv == dv);
        xnv[i][r] = ok ? dv : 0.0f;
        mmv[i][r] = ok ? 1.0f : 0.0f;
      }
    }
    f16x8 mA[4];
    {
      const float* mrow = data + ((size_t)(rowg + l15)*256 + t)*128 + lq*8;
      #pragma unroll
      for (int k=0;k<4;k++){
        float4 a0 = *(const float4*)(mrow + k*32);
        float4 a1 = *(const float4*)(mrow + k*32 + 4);
        f16x8 mv;
        mv[0] = (a0.x==a0.x)?(_Float16)1.0f:(_Float16)0.0f;
        mv[1] = (a0.y==a0.y)?(_Float16)1.0f:(_Float16)0.0f;
        mv[2] = (a0.z==a0.z)?(_Float16)1.0f:(_Float16)0.0f;
        mv[3] = (a0.w==a0.w)?(_Float16)1.0f:(_Float16)0.0f;
        mv[4] = (a1.x==a1.x)?(_Float16)1.0f:(_Float16)0.0f;
        mv[5] = (a1.y==a1.y)?(_Float16)1.0f:(_Float16)0.0f;
        mv[6] = (a1.z==a1.z)?(_Float16)1.0f:(_Float16)0.0f;
        mv[7] = (a1.w==a1.w)?(_Float16)1.0f:(_Float16)0.0f;
        mA[k] = mv;
      }
    }
    // gamma_h(t+1): fully h-independent, hoisted into the wait window.
    // Parity-double-buffered (no b4): write slot (t+1)&1, read same slot in
    // THIS iteration's epilogue; b1..b3 separate write from read.
    if (wv == 0 && t < 255) {
      f16x8 dA[4];
      #pragma unroll
      for (int k=0;k<4;k++)
        dA[k] = *(const f16x8*)(dbf + ((size_t)(rowg+l15)*256 + (t+1))*128 + k*32 + lq*8);
      f32x4 ga = {0.f,0.f,0.f,0.f};
      #pragma unroll
      for (int k=0;k<4;k++)
        ga = __builtin_amdgcn_mfma_f32_16x16x32_f16(dA[k], WdB[k], ga, 0,0,0);
      #pragma unroll
      for (int r=0;r<4;r++)
        ghL[(t+1)&1][lq*4 + r][l15] = __expf(-fmaxf(ga[r] + bdh_s[l15], 0.0f));
    }

    // ---- wait for h(t): all 128 subtags >= t ----
    if (t > 0) {
      if (mode == 0) {
        if (wv == 3) {
          // single poller: 32 lanes x dwordx4 covers all 128 subtags, busy-spin
          for (;;) {
            bool ok = true;
            if (ln < 32) {
              u32x4 tv = __builtin_nontemporal_load((const u32x4*)(tag + ((bt<<5) + ln)*16));
              ok = tv[0] >= (unsigned)t && tv[1] >= (unsigned)t &&
                   tv[2] >= (unsigned)t && tv[3] >= (unsigned)t;
            }
            __asm__ __volatile__("" ::: "memory");
            if (__ballot(ok) == ~0ull) break;
          }
          if (ln == 0)
            __hip_atomic_store(&hrdy, (unsigned)t, __ATOMIC_RELAXED,
                               __HIP_MEMORY_SCOPE_WORKGROUP);
        } else {
          // LDS relay spin: no L2 traffic, fast wake
          while (__hip_atomic_load(&hrdy, __ATOMIC_RELAXED,
                                   __HIP_MEMORY_SCOPE_WORKGROUP) < (unsigned)t) {}
        }
      } else if (mode == 1) {
        for (;;) {
          if (ln < 32)
            __builtin_amdgcn_global_load_lds((const AS1 void*)(tag + ((bt<<5) + ln)*16),
                (AS3 void*)&sbounce[wv][0], 16, 0, 1 /*sc0*/);
          __asm__ __volatile__("" ::: "memory");
          __builtin_amdgcn_s_waitcnt(0);
          __asm__ __volatile__("" ::: "memory");
          bool ok = true;
          if (ln < 32)
            ok = sbounce[wv][ln*4+0] >= (unsigned)t && sbounce[wv][ln*4+1] >= (unsigned)t &&
                 sbounce[wv][ln*4+2] >= (unsigned)t && sbounce[wv][ln*4+3] >= (unsigned)t;
          if (__ballot(ok) == ~0ull) break;
          __builtin_amdgcn_s_sleep(1);
        }
      } else {
        for (;;) {
          // each lane checks 2 of the 128 subtags
          const unsigned int* p = tag + ((bt<<5) + (ln>>1))*16 + (ln&1)*2;
          unsigned v0 = __hip_atomic_load(p,     __ATOMIC_RELAXED, __HIP_MEMORY_SCOPE_AGENT);
          unsigned v1 = __hip_atomic_load(p + 1, __ATOMIC_RELAXED, __HIP_MEMORY_SCOPE_AGENT);
          bool ok = v0 >= (unsigned)t && v1 >= (unsigned)t;
          if (__ballot(ok) == ~0ull) break;
          __builtin_amdgcn_s_sleep(1);
        }
      }
    }

    // ---- h A-fragments ----
    f16x8 hA[16];
    const char* hbB = (const char*)hbuf + (size_t)(((t&1)*8 + bt))*16384;
    if (mode == 0) {
      // direct nt loads: fragment-order layout is lane-linear (ln*16 per ks)
      #pragma unroll
      for (int ks=0;ks<16;ks++) {
        u32x4 hv = __builtin_nontemporal_load((const u32x4*)(hbB + ks*1024 + ln*16));
        hA[ks] = __builtin_bit_cast(f16x8, hv);
      }
    } else if (mode == 1) {
      #pragma unroll
      for (int s=0;s<4;s++){
        int off = s*4096 + wv*1024;
        __builtin_amdgcn_global_load_lds((const AS1 void*)(hbB + off + ln*16),
            (AS3 void*)((char*)hstage + off), 16, 0, 1 /*sc0*/);
      }
      __asm__ __volatile__("" ::: "memory");
      __builtin_amdgcn_s_waitcnt(0);
      __syncthreads();
      #pragma unroll
      for (int ks=0;ks<16;ks++)
        hA[ks] = *(const f16x8*)((const char*)hstage + ks*1024 + ln*16);
    } else {
      #pragma unroll
      for (int ks=0;ks<16;ks++) {
        const char* p = hbB + (size_t)(ks*64 + ln)*16;
        union { unsigned long long u[2]; f16x8 v; } cv;
        cv.u[0] = __hip_atomic_load((const unsigned long long*)p,
                                    __ATOMIC_RELAXED, __HIP_MEMORY_SCOPE_AGENT);
        cv.u[1] = __hip_atomic_load((const unsigned long long*)(p + 8),
                                    __ATOMIC_RELAXED, __HIP_MEMORY_SCOPE_AGENT);
        hA[ks] = cv.v;
      }
    }

    // ---- MFMAs: m-part first (executes under h nt-load shadow), then
    //      x_h chains + gate h-parts (6 concurrent accums) ----
    f32x4 g0 = {0.f,0.f,0.f,0.f}, g1 = {0.f,0.f,0.f,0.f};
    #pragma unroll
    for (int k=0;k<4;k++)
      g0 = __builtin_amdgcn_mfma_f32_16x16x32_f16(mA[k], GB[4+k], g0, 0,0,0);
    f32x4 xA0[2], xA1[2];
    #pragma unroll
    for (int i=0;i<2;i++){
      f32x4 a0 = {0.f,0.f,0.f,0.f}, a1 = {0.f,0.f,0.f,0.f};
      #pragma unroll
      for (int ks=0;ks<8;ks++){
        a0 = __builtin_amdgcn_mfma_f32_16x16x32_f16(hA[ks],   WhB[i][ks],   a0, 0,0,0);
        a1 = __builtin_amdgcn_mfma_f32_16x16x32_f16(hA[ks+8], WhB[i][ks+8], a1, 0,0,0);
      }
      xA0[i] = a0; xA1[i] = a1;
    }
    #pragma unroll
    for (int ks=0;ks<8;ks++)
      g0 = __builtin_amdgcn_mfma_f32_16x16x32_f16(hA[ks], GB[8+ks], g0, 0,0,0);
    #pragma unroll
    for (int ks=0;ks<8;ks++)
      g1 = __builtin_amdgcn_mfma_f32_16x16x32_f16(hA[8+ks], GB[16+ks], g1, 0,0,0);

    // ---- x_h epilogue: sigmoid, loss1, x_c -> xcT ----
    float xhv[2][4];
    float numer = 0.0f;
    #pragma unroll
    for (int i=0;i<2;i++){
      int col = (2*wv+i)*16 + l15;
      float bhc = bh_s[col];
      #pragma unroll
      for (int r=0;r<4;r++){
        float s = sigm(xA0[i][r] + xA1[i][r] + bhc);
        xhv[i][r] = s;
        numer += fabsf(xnv[i][r] - s) * mmv[i][r];
        float xc = (mmv[i][r] > 0.f) ? xnv[i][r] : s;
        xcT[lq*4 + r][col] = (_Float16)xc;
      }
    }
    __syncthreads();                               // b1

    // ---- z_h MFMAs ----
    f16x8 xcA[4];
    #pragma unroll
    for (int k=0;k<4;k++)
      xcA[k] = *(const f16x8*)(&xcT[l15][k*32 + lq*8]);
    f32x4 z0 = {0.f,0.f,0.f,0.f}, z1 = {0.f,0.f,0.f,0.f};
    #pragma unroll
    for (int ks=0;ks<4;ks++){
      z0 = __builtin_amdgcn_mfma_f32_16x16x32_f16(xcA[ks], WfB[0][ks], z0, 0,0,0);
      z1 = __builtin_amdgcn_mfma_f32_16x16x32_f16(xcA[ks], WfB[1][ks], z1, 0,0,0);
    }

    // ---- z_h epilogue: loss2, c_c (fp32 to ccF, f16 to ccT) ----
    #pragma unroll
    for (int i=0;i<2;i++){
      f32x4 a = (i==0) ? z0 : z1;
      int col = (2*wv+i)*16 + l15;
      float bfc = bf_s[col];
      #pragma unroll
      for (int r=0;r<4;r++){
        float z = sigm(a[r] + bfc);
        numer += fabsf(xnv[i][r] - z) * mmv[i][r];
        float chv = fabsf(0.5f*z + 0.5f*xhv[i][r]);
        float cc  = (mmv[i][r] > 0.f) ? xnv[i][r] : chv;
        int row = lq*4 + r;
        ccT[row][col] = (_Float16)cc;
        ccF[row][col] = cc;
      }
    }
    if (ch == 0) loss_acc += numer * invms[t];
    __syncthreads();                               // b2

    // ---- gates: add c_c part, stash per-gate partials ----
    f16x8 ccA[4];
    #pragma unroll
    for (int k=0;k<4;k++)
      ccA[k] = *(const f16x8*)(&ccT[l15][k*32 + lq*8]);
    #pragma unroll
    for (int k=0;k<4;k++)
      g0 = __builtin_amdgcn_mfma_f32_16x16x32_f16(ccA[k], GB[k], g0, 0,0,0);
    #pragma unroll
    for (int r=0;r<4;r++) gbuf[wv][lq*4 + r][l15] = g0[r] + g1[r];
    __syncthreads();                               // b3

    // ---- parallel epilogue: per-wave h publish + per-wave subtag; NO b4.
    //      Cross-iteration LDS hazards are covered by the b1/b2/b3 chain. ----
    {
      float ii = gbuf[0][erow][ecol] + bg_s[0][ecol];
      float ff = gbuf[1][erow][ecol] + bg_s[1][ecol];
      float gg = gbuf[2][erow][ecol] + bg_s[2][ecol];
      float oo = gbuf[3][erow][ecol] + bg_s[3][ecol];
      float cn = sigm(ff)*c_reg + sigm(ii)*tanh_(gg);
      c_reg = cn;
      if (t < 255) {
        float hn = sigm(oo)*tanh_(cn) * ghL[(t+1)&1][erow][ecol];
        _Float16 hf = (_Float16)hn;
        char* dp = (char*)hbuf + (size_t)((((t+1)&1)*8 + bt))*16384 + e2*2;
        unsigned tv = (unsigned)(t+1);
        if (mode < 2) {
          *(_Float16*)dp = hf;                     // coalesced 64B-line stores
          __asm__ __volatile__("" ::: "memory");
          __builtin_amdgcn_s_waitcnt(0);           // this wave's h in L2 ...
          __asm__ __volatile__("" ::: "memory");
          if (ln == 0) tagw[wv] = tv;              // ... before its subtag
          __asm__ __volatile__("" ::: "memory");
        } else {
          union { _Float16 f; unsigned short u; } cv2; cv2.f = hf;
          __hip_atomic_store((unsigned short*)dp, cv2.u,
                             __ATOMIC_RELAXED, __HIP_MEMORY_SCOPE_AGENT);
          __atomic_signal_fence(__ATOMIC_SEQ_CST);
          __builtin_amdgcn_s_waitcnt(0);
          __atomic_signal_fence(__ATOMIC_SEQ_CST);
          if (ln == 0)
            __hip_atomic_store(tagw + wv, tv,
                               __ATOMIC_RELAXED, __HIP_MEMORY_SCOPE_AGENT);
        }
      }
    }
    // out-stores issued AFTER the subtag store: fire-and-forget into the
    // next poll window
    if (wv == 1) {
      int row = ln >> 2, col = ch*4 + (ln & 3);
      out[1 + ((size_t)(rowg+row)*256 + t)*128 + col] = ccF[row][col];
    }
  }

  // ---- loss reduction (chunk-0 blocks only) ----
  if (ch == 0) {
    red[tid] = loss_acc;
    __syncthreads();
    if (tid == 0) {
      float s = 0.f;
      for (int i=0;i<256;i++) s += red[i];
      atomicAdd(out, 0.3f * s);
    }
  }
}

// ---------------- launch ----------------

extern "C" void kernel_launch(void* const* d_in, const int* in_sizes, int n_in,
                              void* d_out, int out_size, void* d_ws, size_t ws_size,
                              hipStream_t stream) {
  const float* data = (const float*)d_in[0];
  const float* W_ih = (const float*)d_in[1];
  const float* b_ih = (const float*)d_in[2];
  const float* W_hh = (const float*)d_in[3];
  const float* b_hh = (const float*)d_in[4];
  const float* Wdh  = (const float*)d_in[5];
  const float* bdh  = (const float*)d_in[6];
  // d_in[7] Wdx, d_in[8] bdx: dead code in reference forward
  const float* Wh   = (const float*)d_in[9];
  const float* bh   = (const float*)d_in[10];
  const float* Wf   = (const float*)d_in[11];
  const float* bf   = (const float*)d_in[12];
  // d_in[13] Wc, d_in[14] bc: dead code
  float* out = (float*)d_out;
  unsigned char* ws = (unsigned char*)d_ws;

  k_prep     <<<7432, 256, 0, stream>>>(data, W_ih, W_hh, Wdh, Wh, Wf,
                                        b_ih, b_hh, ws, out);
  brits_main <<<256,  256, 0, stream>>>(data, bh, bf, bdh, ws, out);
}